// Round 14
// baseline (226.718 us; speedup 1.0000x reference)
//
#include <hip/hip_runtime.h>
#include <hip/hip_bf16.h>

#define H 2
#define C 64
#define IN_CH 64
#define HC (H*C)
#define NEG_SLOPE 0.2f
#define NBUCK_MAX 256
#define SBLK 512      // scatter blocks
#define CAP 12288     // per-bucket staging capacity (mean 8163, sigma ~90 -> safe)

// ================= K1: projection + attention dots (+ cnt zero) =================
__global__ __launch_bounds__(128) void proj_kernel(
    const float* __restrict__ x, const float* __restrict__ W,
    const float* __restrict__ att_src, const float* __restrict__ att_dst,
    __hip_bfloat16* __restrict__ xp, float* __restrict__ asrc,
    float* __restrict__ adst, int* __restrict__ cnt, int N, int nbuck) {
    int t = threadIdx.x;  // output channel 0..127
    if (blockIdx.x == 0)  // zero bucket counters for the (later) scatter dispatch
        for (int i = t; i < nbuck; i += 128) cnt[i] = 0;
    float w[64];
    const float4* wr = reinterpret_cast<const float4*>(W + (size_t)t * IN_CH);
#pragma unroll
    for (int q = 0; q < 16; q++) {
        float4 v = wr[q];
        w[4 * q] = v.x; w[4 * q + 1] = v.y; w[4 * q + 2] = v.z; w[4 * q + 3] = v.w;
    }
    float a_s = att_src[t], a_d = att_dst[t];
    int lane = t & 63, head = t >> 6;
    for (int n = blockIdx.x; n < N; n += gridDim.x) {
        const float* xr = x + (size_t)n * IN_CH;  // wave-uniform address -> s_load
        float acc = 0.f;
#pragma unroll
        for (int k = 0; k < 64; k++) acc = fmaf(w[k], xr[k], acc);
        xp[(size_t)n * HC + t] = __float2bfloat16(acc);
        float as = acc * a_s, ad = acc * a_d;
#pragma unroll
        for (int d = 32; d > 0; d >>= 1) {
            as += __shfl_xor(as, d, 64);
            ad += __shfl_xor(ad, d, 64);
        }
        if (lane == 0) {
            asrc[(size_t)n * H + head] = as;
            adst[(size_t)n * H + head] = ad;
        }
    }
}

// ================= K2: bucket hist + reservation + scatter =================
__global__ __launch_bounds__(256) void scatter_kernel(
    const int* __restrict__ edge, int* __restrict__ cnt,
    int* __restrict__ staged, int N, int E) {
    const int tid = threadIdx.x, bid = blockIdx.x;
    const int nbuck = (N + 255) >> 8;
    const int chunkE = (E + SBLK - 1) / SBLK;
    const int* srcE = edge;
    const int* dstE = edge + E;
    __shared__ int lh[NBUCK_MAX], bse[NBUCK_MAX], lcur[NBUCK_MAX];
    for (int i = tid; i < nbuck; i += 256) { lh[i] = 0; lcur[i] = 0; }
    __syncthreads();
    int beg = bid * chunkE, end = min(beg + chunkE, E);
    for (int i = beg + tid; i < end; i += 256)
        atomicAdd(&lh[dstE[i] >> 8], 1);
    __syncthreads();
    for (int i = tid; i < nbuck; i += 256) {
        int c = lh[i];
        bse[i] = (c > 0) ? atomicAdd(&cnt[i], c) : 0;  // reserve [bse, bse+c)
    }
    __syncthreads();
    for (int i = beg + tid; i < end; i += 256) {
        int s = srcE[i], d = dstE[i];
        int b = d >> 8;
        int l = atomicAdd(&lcur[b], 1);
        staged[(size_t)b * CAP + bse[b] + l] = s | ((d & 255) << 20);  // src < 2^20
    }
}

// ================= K3: CSR finalize + per-edge weights + per-node denominators ======
// nbuck blocks x 512 thr. Computes w = exp(leaky(asrc[s]+adst[d])) per edge into
// wts[] (aligned with csr), and den[n] = sum of edge weights + self-loop weight.
__global__ __launch_bounds__(512) void csr_weights_kernel(
    const int* __restrict__ staged, const int* __restrict__ cnt,
    const float2* __restrict__ asrc, const float2* __restrict__ adst,
    int* __restrict__ off, int* __restrict__ csr, float2* __restrict__ wts,
    float2* __restrict__ den, int N, int nbuck) {
    int b = blockIdx.x, t = threadIdx.x;
    __shared__ int bse[256], rs[256], lh[256], sh[256], cur[256];
    __shared__ float2 adL[256];
    __shared__ float denS[512];  // [2*dl] = head0, [2*dl+1] = head1
    {   // exclusive scan of cnt[nbuck] -> bse
        int v = (t < nbuck) ? cnt[t] : 0;
        if (t < 256) { bse[t] = v; rs[t] = v; }
        __syncthreads();
        for (int d = 1; d < 256; d <<= 1) {
            int u = (t >= d && t < 256) ? bse[t - d] : 0;
            __syncthreads();
            if (t < 256) bse[t] += u;
            __syncthreads();
        }
        if (t < 256) bse[t] -= rs[t];
        __syncthreads();
    }
    int base = bse[b], size = rs[b];
    const int* st = staged + (size_t)b * CAP;
    if (t < 256) {
        lh[t] = 0;
        int nd = b * 256 + t;
        if (nd < N) {
            float2 ad = adst[nd];
            adL[t] = ad;
            float2 asn = asrc[nd];
            float e0 = asn.x + ad.x; e0 = (e0 > 0.f) ? e0 : NEG_SLOPE * e0;
            float e1 = asn.y + ad.y; e1 = (e1 > 0.f) ? e1 : NEG_SLOPE * e1;
            denS[2 * t] = __expf(e0);      // self-loop weight seeds denominator
            denS[2 * t + 1] = __expf(e1);
        } else {
            adL[t] = make_float2(0.f, 0.f);
            denS[2 * t] = 1.f;
            denS[2 * t + 1] = 1.f;
        }
    }
    __syncthreads();
    for (int i = t; i < size; i += 512)
        atomicAdd(&lh[st[i] >> 20], 1);
    __syncthreads();
    int v = (t < 256) ? lh[t] : 0;
    if (t < 256) sh[t] = v;
    __syncthreads();
    for (int d = 1; d < 256; d <<= 1) {
        int u = (t >= d && t < 256) ? sh[t - d] : 0;
        __syncthreads();
        if (t < 256) sh[t] += u;
        __syncthreads();
    }
    if (t < 256) {
        int ex = sh[t] - v;
        int nd = b * 256 + t;
        if (nd < N) off[nd] = base + ex;
        if (nd == N - 1) off[N] = base + size;
        cur[t] = base + ex;
    }
    __syncthreads();
    for (int i = t; i < size; i += 512) {
        int e = st[i];
        int s = e & 0xFFFFF, dl = e >> 20;
        float2 as = asrc[s];
        float2 ad = adL[dl];
        float e0 = as.x + ad.x; e0 = (e0 > 0.f) ? e0 : NEG_SLOPE * e0;
        float e1 = as.y + ad.y; e1 = (e1 > 0.f) ? e1 : NEG_SLOPE * e1;
        float w0 = __expf(e0), w1 = __expf(e1);
        int pos = atomicAdd(&cur[dl], 1);
        csr[pos] = s;
        wts[pos] = make_float2(w0, w1);
        atomicAdd(&denS[2 * dl], w0);
        atomicAdd(&denS[2 * dl + 1], w1);
    }
    __syncthreads();
    if (t < 256) {
        int nd = b * 256 + t;
        if (nd < N) den[nd] = make_float2(denS[2 * t], denS[2 * t + 1]);
    }
}

// -------- gather+FMA over NB*8 staged edges, all loads issued before FMAs --------
template<int NB>
__device__ __forceinline__ void gather_fma(const uint* __restrict__ xpw,
                                           const int* __restrict__ sidx,
                                           const float2* __restrict__ swt,
                                           int lane, float& accx, float& accy) {
    uint bu[NB * 8];
#pragma unroll
    for (int j = 0; j < NB * 8; j++) {
        int s2 = sidx[j];
        bu[j] = xpw[(size_t)s2 * 64 + lane];
    }
#pragma unroll
    for (int j = 0; j < NB * 8; j++) {
        float2 wv = swt[j];
        float wgt = (lane < 32) ? wv.x : wv.y;
        accx = fmaf(wgt, __uint_as_float(bu[j] << 16), accx);
        accy = fmaf(wgt, __uint_as_float(bu[j] & 0xffff0000u), accy);
    }
}

// ================= K4: aggregation only (weights precomputed) =================
__global__ __launch_bounds__(256, 4) void aggregate_kernel(
    const __hip_bfloat16* __restrict__ xp, const float2* __restrict__ asrc,
    const float2* __restrict__ adst, const int* __restrict__ off,
    const int* __restrict__ csr, const float2* __restrict__ wts,
    const float2* __restrict__ den, const float* __restrict__ bias,
    float* __restrict__ out, int N) {
    __shared__ int sidx[4][64];
    __shared__ float2 swt[4][64];
    int wid = threadIdx.x >> 6;
    int n = blockIdx.x * 4 + wid;
    if (n >= N) return;
    int lane = threadIdx.x & 63;
    int* si = sidx[wid];
    float2* sw = swt[wid];
    int o0 = off[n];
    int degE = off[n + 1] - o0;  // real edges only (self-loop analytic)
    float2 dn = den[n];
    float2 ad = adst[n];
    float2 asn = asrc[n];
    float es0 = asn.x + ad.x; es0 = (es0 > 0.f) ? es0 : NEG_SLOPE * es0;
    float es1 = asn.y + ad.y; es1 = (es1 > 0.f) ? es1 : NEG_SLOPE * es1;
    float ws0 = __expf(es0), ws1 = __expf(es1);

    const uint* xpw = reinterpret_cast<const uint*>(xp);
    float accx, accy;
    {   // self-loop contribution
        float wgt = (lane < 32) ? ws0 : ws1;
        uint u = xpw[(size_t)n * 64 + lane];
        accx = wgt * __uint_as_float(u << 16);
        accy = wgt * __uint_as_float(u & 0xffff0000u);
    }

    for (int base = 0; base < degE; base += 64) {
        int i = base + lane;
        int idx = 0;
        float2 w2 = make_float2(0.f, 0.f);
        if (i < degE) {
            idx = csr[o0 + i];      // coalesced
            w2 = wts[o0 + i];       // coalesced
        }
        si[lane] = idx;
        sw[lane] = w2;
        int cnt2 = min(degE - base, 64);
        int nb8 = (cnt2 + 7) >> 3;  // padded slots carry w=0, idx=0 (harmless)
        switch (nb8) {
            case 1: gather_fma<1>(xpw, si, sw, lane, accx, accy); break;
            case 2: gather_fma<2>(xpw, si, sw, lane, accx, accy); break;
            case 3: gather_fma<3>(xpw, si, sw, lane, accx, accy); break;
            case 4: gather_fma<4>(xpw, si, sw, lane, accx, accy); break;
            case 5: gather_fma<5>(xpw, si, sw, lane, accx, accy); break;
            case 6: gather_fma<6>(xpw, si, sw, lane, accx, accy); break;
            case 7: gather_fma<7>(xpw, si, sw, lane, accx, accy); break;
            default: gather_fma<8>(xpw, si, sw, lane, accx, accy); break;
        }
    }
    float inv = (lane < 32) ? (1.f / dn.x) : (1.f / dn.y);
    accx *= inv;
    accy *= inv;
    float ox = 0.5f * (accx + __shfl_xor(accx, 32, 64));
    float oy = 0.5f * (accy + __shfl_xor(accy, 32, 64));
    if (lane < 32) {
        float vx = ox + bias[2 * lane];
        float vy = oy + bias[2 * lane + 1];
        *reinterpret_cast<float2*>(out + (size_t)n * C + 2 * lane) = make_float2(vx, vy);
    }
}

// ================= K5: pool = segment mean (sorted batch), 4 row-streams =================
__global__ __launch_bounds__(256) void pool_kernel(const float* __restrict__ hn,
                                                   const int* __restrict__ batch,
                                                   float* __restrict__ outG, int N, int G) {
    int g = blockIdx.x;
    int c = threadIdx.x & 63, r = threadIdx.x >> 6;  // 4 parallel row streams
    int lo = 0, hi = N;
    while (lo < hi) { int mid = (lo + hi) >> 1; if (batch[mid] < g) lo = mid + 1; else hi = mid; }
    int beg = lo;
    hi = N;
    while (lo < hi) { int mid = (lo + hi) >> 1; if (batch[mid] <= g) lo = mid + 1; else hi = mid; }
    int end = lo;
    float s = 0.f;
    for (int n = beg + r; n < end; n += 4) s += hn[(size_t)n * C + c];
    __shared__ float red[256];
    red[threadIdx.x] = s;
    __syncthreads();
    if (r == 0) {
        float tot = red[c] + red[64 + c] + red[128 + c] + red[192 + c];
        outG[(size_t)g * C + c] = tot / fmaxf((float)(end - beg), 1.f);
    }
}

extern "C" void kernel_launch(void* const* d_in, const int* in_sizes, int n_in,
                              void* d_out, int out_size, void* d_ws, size_t ws_size,
                              hipStream_t stream) {
    const float* x       = (const float*)d_in[0];
    const int*   edge    = (const int*)d_in[1];
    const int*   batch   = (const int*)d_in[2];
    const float* W       = (const float*)d_in[3];
    const float* att_src = (const float*)d_in[4];
    const float* att_dst = (const float*)d_in[5];
    const float* bias    = (const float*)d_in[6];

    int N = in_sizes[0] / IN_CH;
    int E = in_sizes[1] / 2;
    int G = out_size / C - N;
    int nbuck = (N + 255) >> 8;            // 196 for N=50000 (must be <= 256)

    char* p = (char*)d_ws;
    auto alloc = [&](size_t bytes) {
        char* r = p;
        p += (bytes + 255) & ~(size_t)255;
        return r;
    };
    __hip_bfloat16* xp = (__hip_bfloat16*)alloc((size_t)N * HC * 2);
    float* asrc    = (float*)alloc((size_t)N * H * 4);
    float* adst    = (float*)alloc((size_t)N * H * 4);
    int*   cnt     = (int*)alloc((size_t)nbuck * 4);
    int*   off     = (int*)alloc((size_t)(N + 1) * 4);
    int*   staged  = (int*)alloc((size_t)nbuck * CAP * 4);
    int*   csr     = (int*)alloc((size_t)E * 4);
    float2* wts    = (float2*)alloc((size_t)E * 8);
    float2* den    = (float2*)alloc((size_t)N * 8);

    proj_kernel<<<2048, 128, 0, stream>>>(x, W, att_src, att_dst, xp, asrc, adst,
                                          cnt, N, nbuck);
    scatter_kernel<<<SBLK, 256, 0, stream>>>(edge, cnt, staged, N, E);
    csr_weights_kernel<<<nbuck, 512, 0, stream>>>(staged, cnt, (const float2*)asrc,
                                                  (const float2*)adst, off, csr, wts, den,
                                                  N, nbuck);
    aggregate_kernel<<<(N + 3) / 4, 256, 0, stream>>>(xp, (const float2*)asrc,
                                                      (const float2*)adst, off, csr, wts, den,
                                                      bias, (float*)d_out, N);
    pool_kernel<<<G, 256, 0, stream>>>((const float*)d_out, batch,
                                       (float*)d_out + (size_t)N * C, N, G);
}